// Round 8
// baseline (996.917 us; speedup 1.0000x reference)
//
#include <hip/hip_runtime.h>

#define SEQT  512
#define BM    16          // LDS layout cols (MFMA N) — fixed at 16
#define BREAL 8           // real batches per block; cols 8..15 are pad
#define NW    7           // waves; wave w owns gate-tiles 2w, 2w+1 (tile 13 = pad)
#define NT    (NW * 64)   // 448 threads
#define ROWB  256         // bytes per batch-row: 128 k-slots * 2B
#define HBUF  4096        // one buffer: 16 rows * 256B

typedef _Float16 half8  __attribute__((ext_vector_type(8)));
typedef _Float16 half4v __attribute__((ext_vector_type(4)));
typedef float    f32x4  __attribute__((ext_vector_type(4)));

__device__ __forceinline__ float fast_rcp(float x) { return __builtin_amdgcn_rcpf(x); }
__device__ __forceinline__ float sigm(float x) { return fast_rcp(1.f + __expf(-x)); }
// tanh via exp; saturates correctly (exp->inf -> rcp->0 -> 1)
__device__ __forceinline__ float tanh_f(float x) { return 1.f - 2.f * fast_rcp(__expf(2.f * x) + 1.f); }

#define MFMA16(A, B, C) __builtin_amdgcn_mfma_f32_16x16x32_f16((A), (B), (C), 0, 0, 0)

// k-layout of one h-buffer row (128 fp16 slots per batch m):
//   k 0..49  h0 units   k 52..54 x_t   k 55 const 1.0   k 64..113 h1 units   else 0
// Phase t: L0(t) || L1(t-1); both read buf[rb], write buf[wb]; ONE barrier per phase.
// BREAL=8: 512 blocks -> 2 independent barrier groups per CU (latency overlap).
// Cols 8..15 are pad batches: zero x/bias columns -> deterministic values, discarded.
// C-frag: row=(lane>>4)*4+reg, col=lane&15; gate-perm n=4u+g. A-frag: row=lane&15,
// k=(lane>>4)*8+j.

__global__ __launch_bounds__(NT) void lstm2_mfma6(
    const float* __restrict__ x,
    const float* __restrict__ Wih0, const float* __restrict__ Whh0,
    const float* __restrict__ bih0, const float* __restrict__ bhh0,
    const float* __restrict__ Wih1, const float* __restrict__ Whh1,
    const float* __restrict__ bih1, const float* __restrict__ bhh1,
    const float* __restrict__ Wfc,  const float* __restrict__ bfc,
    float* __restrict__ out)
{
    __shared__ __align__(16) char hb[2 * HBUF];
    __shared__ float fcbuf[NW][BM];

    const int tid = threadIdx.x;
    const int l   = tid & 63, w = tid >> 6;      // w = wave 0..6
    const int m   = l & 15,  g4 = l >> 4;
    const int b0  = blockIdx.x * BREAL;
    const int swz = (m & 7) << 4;
    const bool hasT1 = (w < 6);                  // tile 2w+1 real iff < 13

    // ---------------- A-fragments (single fp16), two tiles ----------------
    half8 a0[2][2];      // L0: K=64  (Whh0 | x-cols 52..54 | bias-col 55)
    half8 a1[2][4];      // L1: K=128 (Wih1 | bias-col 55 | Whh1 at 64..113)
    float wfcv[2];
    int   ucv[2];
    bool  wok[2];
#pragma unroll
    for (int tt = 0; tt < 2; ++tt) {
        const int T  = 2 * w + tt;
        const int nA = T * 16 + m;               // A-frag gate-row
        const int uA = nA >> 2, gA = nA & 3;
        const bool ok = uA < 50;
        const int rA = gA * 50 + (ok ? uA : 0);
#pragma unroll
        for (int kt = 0; kt < 2; ++kt) {
            half8 v;
#pragma unroll
            for (int j = 0; j < 8; ++j) {
                const int k = kt * 32 + g4 * 8 + j;
                float f = 0.f;
                if (ok) {
                    if (k < 50)                 f = Whh0[rA * 50 + k];
                    else if (k >= 52 && k < 55) f = Wih0[rA * 3 + (k - 52)];
                    else if (k == 55)           f = bih0[rA] + bhh0[rA];
                }
                v[j] = (_Float16)f;
            }
            a0[tt][kt] = v;
        }
#pragma unroll
        for (int kt = 0; kt < 4; ++kt) {
            half8 v;
#pragma unroll
            for (int j = 0; j < 8; ++j) {
                const int k = kt * 32 + g4 * 8 + j;
                float f = 0.f;
                if (ok) {
                    if (k < 50)                  f = Wih1[rA * 50 + k];
                    else if (k == 55)            f = bih1[rA] + bhh1[rA];
                    else if (k >= 64 && k < 114) f = Whh1[rA * 50 + (k - 64)];
                }
                v[j] = (_Float16)f;
            }
            a1[tt][kt] = v;
        }
        const int uc = T * 4 + g4;               // this lane's output unit for tile tt
        ucv[tt]  = uc;
        wok[tt]  = (uc < 50);                    // pads must NOT write (k 52..55 = x/bias!)
        wfcv[tt] = (uc < 50) ? Wfc[uc] : 0.f;
    }

    // ---------------- loop-invariant LDS byte offsets ----------------
    int rd[4], wr0[2], wr1[2];
#pragma unroll
    for (int q = 0; q < 4; ++q) rd[q] = m * ROWB + (((q * 4 + g4) * 16) ^ swz);
#pragma unroll
    for (int tt = 0; tt < 2; ++tt) {
        wr0[tt] = m * ROWB + ((ucv[tt] * 2) ^ swz);          // h0 slot k=uc
        wr1[tt] = m * ROWB + (((64 + ucv[tt]) * 2) ^ swz);   // h1 slot k=64+uc
    }
    const int wrx = m * ROWB + (104 ^ swz);                  // x slots k=52..55 (8B)

    // ---------------- init: zero buffers, plant x(0) and the 1.0 column ----------------
    for (int i = tid; i < 2 * HBUF / 4; i += NT) ((int*)hb)[i] = 0;
    __syncthreads();
    const bool xlane = (w == 0) && (g4 == 0) && (m < BREAL);   // 8 lanes, m = real batch
    const float* xbase = x + (size_t)(b0 + (m < BREAL ? m : 0)) * (SEQT * 3);
    const _Float16 onef = (_Float16)1.f;
    if (xlane) {
        half4v xv;
        xv[0] = (_Float16)xbase[0]; xv[1] = (_Float16)xbase[1];
        xv[2] = (_Float16)xbase[2]; xv[3] = onef;
        *(half4v*)(hb + HBUF + wrx) = xv;        // buf1: x(0)+1.0 (phase 0 reads buf1)
        half4v z; z[0] = (_Float16)0.f; z[1] = z[0]; z[2] = z[0]; z[3] = onef;
        *(half4v*)(hb + wrx) = z;                // buf0: 1.0 column
    }
    float c0[2] = {0.f, 0.f}, c1[2] = {0.f, 0.f}, h1v[2] = {0.f, 0.f};
    __syncthreads();

    const f32x4 z4 = {0.f, 0.f, 0.f, 0.f};

    // ---------------- one phase: L0(t) || L1(t-1), single barrier ----------------
    auto phase = [&](int rb, int wb, bool doL1, bool doX, int t) {
        const half8 bf0 = *(const half8*)(hb + rb + rd[0]);
        const half8 bf1 = *(const half8*)(hb + rb + rd[1]);
        const half8 bf2 = *(const half8*)(hb + rb + rd[2]);
        const half8 bf3 = *(const half8*)(hb + rb + rd[3]);

        // ---- MFMAs first: up to 6 independent chains of depth <= 2 ----
        f32x4 gA0, gA1, gB0, gB1;
        gA0 = MFMA16(a0[0][0], bf0, z4); gA0 = MFMA16(a0[0][1], bf1, gA0);
        if (hasT1) { gA1 = MFMA16(a0[1][0], bf0, z4); gA1 = MFMA16(a0[1][1], bf1, gA1); }
        if (doL1) {
            f32x4 p = MFMA16(a1[0][0], bf0, z4); p = MFMA16(a1[0][1], bf1, p);
            f32x4 q = MFMA16(a1[0][2], bf2, z4); q = MFMA16(a1[0][3], bf3, q);
            gB0 = p + q;
            if (hasT1) {
                f32x4 r = MFMA16(a1[1][0], bf0, z4); r = MFMA16(a1[1][1], bf1, r);
                f32x4 s = MFMA16(a1[1][2], bf2, z4); s = MFMA16(a1[1][3], bf3, s);
                gB1 = r + s;
            }
        }

        // ---- activations: tile 0 then tile 1 (independent chains) ----
#pragma unroll
        for (int tt = 0; tt < 2; ++tt) {
            if (tt == 1 && !hasT1) break;
            const f32x4 g0v = (tt == 0) ? gA0 : gA1;
            const float i0 = sigm(g0v[0]), f0 = sigm(g0v[1]);
            const float gg0 = tanh_f(g0v[2]), o0 = sigm(g0v[3]);
            c0[tt] = f0 * c0[tt] + i0 * gg0;
            const float h0 = o0 * tanh_f(c0[tt]);
            if (wok[tt]) *(_Float16*)(hb + wb + wr0[tt]) = (_Float16)h0;
            if (doL1) {
                const f32x4 g1v = (tt == 0) ? gB0 : gB1;
                const float i1 = sigm(g1v[0]), f1 = sigm(g1v[1]);
                const float gg1 = tanh_f(g1v[2]), o1 = sigm(g1v[3]);
                c1[tt] = f1 * c1[tt] + i1 * gg1;
                h1v[tt] = o1 * tanh_f(c1[tt]);
                if (wok[tt]) *(_Float16*)(hb + wb + wr1[tt]) = (_Float16)h1v[tt];
            }
        }
        if (doX && xlane) {                      // stage x(t+1) into the write buffer
            const float* xp = xbase + (t + 1) * 3;
            half4v xv;
            xv[0] = (_Float16)xp[0]; xv[1] = (_Float16)xp[1];
            xv[2] = (_Float16)xp[2]; xv[3] = onef;
            *(half4v*)(hb + wb + wrx) = xv;
        }
        __syncthreads();
    };

    // phase 0: L0(0) only
    phase(HBUF, 0, false, true, 0);
    // phases 1..510
    for (int it = 0; it < 255; ++it) {
        phase(0, HBUF, true, true, 2 * it + 1);
        phase(HBUF, 0, true, true, 2 * it + 2);
    }
    // phase 511 (no x(512) to stage)
    phase(0, HBUF, true, false, 511);

    // epilogue: L1(511) reads buf1 (h0(511), h1(510)); no writes needed
    {
        const half8 bf0 = *(const half8*)(hb + HBUF + rd[0]);
        const half8 bf1 = *(const half8*)(hb + HBUF + rd[1]);
        const half8 bf2 = *(const half8*)(hb + HBUF + rd[2]);
        const half8 bf3 = *(const half8*)(hb + HBUF + rd[3]);
#pragma unroll
        for (int tt = 0; tt < 2; ++tt) {
            if (tt == 1 && !hasT1) break;
            f32x4 p = MFMA16(a1[tt][0], bf0, z4); p = MFMA16(a1[tt][1], bf1, p);
            f32x4 q = MFMA16(a1[tt][2], bf2, z4); q = MFMA16(a1[tt][3], bf3, q);
            const f32x4 g1v = p + q;
            const float i1 = sigm(g1v[0]), f1 = sigm(g1v[1]);
            const float gg1 = tanh_f(g1v[2]), o1 = sigm(g1v[3]);
            c1[tt] = f1 * c1[tt] + i1 * gg1;
            h1v[tt] = o1 * tanh_f(c1[tt]);
        }
    }

    // ---------------- FC head: out[b] = sum_u h1[u]*Wfc[u] + bfc ----------------
    float pv = h1v[0] * wfcv[0] + h1v[1] * wfcv[1];   // pad lanes contribute 0
    pv += __shfl_down(pv, 32, 64);
    pv += __shfl_down(pv, 16, 64);
    if (l < 16) fcbuf[w][l] = pv;
    __syncthreads();
    if (tid < BREAL) {
        float s = bfc[0];
#pragma unroll
        for (int ww = 0; ww < NW; ++ww) s += fcbuf[ww][tid];
        out[b0 + tid] = s;
    }
}

extern "C" void kernel_launch(void* const* d_in, const int* in_sizes, int n_in,
                              void* d_out, int out_size, void* d_ws, size_t ws_size,
                              hipStream_t stream)
{
    const float* x    = (const float*)d_in[0];
    const float* Wih0 = (const float*)d_in[1];
    const float* Whh0 = (const float*)d_in[2];
    const float* bih0 = (const float*)d_in[3];
    const float* bhh0 = (const float*)d_in[4];
    const float* Wih1 = (const float*)d_in[5];
    const float* Whh1 = (const float*)d_in[6];
    const float* bih1 = (const float*)d_in[7];
    const float* bhh1 = (const float*)d_in[8];
    const float* Wfc  = (const float*)d_in[9];
    const float* bfc  = (const float*)d_in[10];
    float* out = (float*)d_out;

    const int B = in_sizes[0] / (SEQT * 3);   // 4096
    lstm2_mfma6<<<B / BREAL, NT, 0, stream>>>(x, Wih0, Whh0, bih0, bhh0,
                                              Wih1, Whh1, bih1, bhh1, Wfc, bfc, out);
}

// Round 10
// 632.066 us; speedup vs baseline: 1.5772x; 1.5772x over previous
//
#include <hip/hip_runtime.h>

#define SEQT 512
#define BM   16           // batch rows per block (MFMA N)
#define NW   4            // waves = SIMDs; units round-robined across waves
#define NT   (NW * 64)    // 256 threads
#define ROWB 256          // bytes per batch-row: 128 k-slots * 2B
#define HBUF 4096         // one buffer: 16 rows * 256B
#define NUNITS 26         // 13 L0 gate-tiles + 13 L1 gate-tiles

typedef _Float16 half8  __attribute__((ext_vector_type(8)));
typedef _Float16 half4v __attribute__((ext_vector_type(4)));
typedef float    f32x4  __attribute__((ext_vector_type(4)));

__device__ __forceinline__ float fast_rcp(float x) { return __builtin_amdgcn_rcpf(x); }

#define MFMA16(A, B, C) __builtin_amdgcn_mfma_f32_16x16x32_f16((A), (B), (C), 0, 0, 0)

// Unit u (0..25): layer = u/13, tile = u%13. Wave w owns units {w, w+4, ...} (7,7,6,6).
// k-layout of one h-buffer row (128 fp16 slots per batch m):
//   k 0..49 h0 units | k 52..54 x_t | k 55 const 1.0 | k 64..113 h1 units | else 0
// Phase t: L0(t) || L1(t-1); reads buf[(t+1)&1], writes buf[t&1]; ONE barrier/phase.
// All waves read the SAME 4 ds_read_b128 (B-frag is unit-independent).
// C-frag: row=(lane>>4)*4+reg, col=lane&15; gate-perm n=4u+g. A-frag: row=lane&15,
// k=(lane>>4)*8+j.
// Activations use rcp-pairing: rcp((1+a)(1+b)) serves two sigmoids (10->8 trans/unit).

// -------- per-wave static phase body (CW = wave id, compile-time) --------
template<int CW>
__device__ __forceinline__ void phase_body(
    int t, const half8* bf, half8 (&af)[7][4], float (&cst)[7],
    char* hbase, int wb, const int (&wrh)[7], const bool (&wok)[7], float (&h1v)[7])
{
    constexpr int NU = (CW < 2) ? 7 : 6;
    const f32x4 z4 = {0.f, 0.f, 0.f, 0.f};
    f32x4 g[7];
    // ---- MFMA chains for all units (independent) ----
#pragma unroll
    for (int idx = 0; idx < NU; ++idx) {
        constexpr int U_BASE = CW;
        const int unit = U_BASE + 4 * idx;        // constexpr-foldable
        if (unit < 13) {                          // layer 0, K=64
            f32x4 a = MFMA16(af[idx][0], bf[0], z4);
            g[idx]  = MFMA16(af[idx][1], bf[1], a);
        } else {                                  // layer 1, K=128, two depth-2 chains
            f32x4 p = MFMA16(af[idx][0], bf[0], z4);
            p       = MFMA16(af[idx][1], bf[1], p);
            f32x4 q = MFMA16(af[idx][2], bf[2], z4);
            q       = MFMA16(af[idx][3], bf[3], q);
            g[idx]  = p + q;
        }
    }
    // ---- activations: 6-7 independent chains, rcp-paired ----
#pragma unroll
    for (int idx = 0; idx < NU; ++idx) {
        const int unit = CW + 4 * idx;
        const bool isL1 = (unit >= 13);
        if (isL1 && t == 0) continue;             // L1(-1) doesn't exist
        const f32x4 gv = g[idx];
        const float Ei = __expf(-gv[0]), Ef = __expf(-gv[1]);
        const float Eg = __expf(2.f * gv[2]), Eo = __expf(-gv[3]);
        const float pi = 1.f + Ei, pf = 1.f + Ef, pg = 1.f + Eg, po = 1.f + Eo;
        const float r1 = fast_rcp(pi * pf);
        const float iv = pf * r1, fv = pi * r1;
        const float r2 = fast_rcp(pg * po);
        const float ov = pg * r2;
        const float tg = 1.f - 2.f * (po * r2);
        const float c  = fv * cst[idx] + iv * tg;
        cst[idx] = c;
        const float Ec = __expf(2.f * c);
        const float hv = ov * (1.f - 2.f * fast_rcp(1.f + Ec));
        if (isL1) h1v[idx] = hv;
        if (wok[idx]) *(_Float16*)(hbase + wb + wrh[idx]) = (_Float16)hv;
    }
}

__global__ __launch_bounds__(NT) void lstm2_mfma7(
    const float* __restrict__ x,
    const float* __restrict__ Wih0, const float* __restrict__ Whh0,
    const float* __restrict__ bih0, const float* __restrict__ bhh0,
    const float* __restrict__ Wih1, const float* __restrict__ Whh1,
    const float* __restrict__ bih1, const float* __restrict__ bhh1,
    const float* __restrict__ Wfc,  const float* __restrict__ bfc,
    float* __restrict__ out)
{
    __shared__ __align__(16) char hb[2 * HBUF];
    __shared__ float h1g[52][BM];                 // final h1 for FC

    const int tid = threadIdx.x;
    const int l   = tid & 63, w = tid >> 6;       // w = 0..3
    const int m   = l & 15,  g4 = l >> 4;
    const int b0  = blockIdx.x * BM;
    const int swz = (m & 7) << 4;

    // ---------------- stage A-fragments for this wave's units ----------------
    half8 af[7][4];
    float cst[7], h1v[7];
    int   wrh[7], ucA[7];
    bool  wok[7];
#pragma unroll
    for (int idx = 0; idx < 7; ++idx) {
        cst[idx] = 0.f; h1v[idx] = 0.f; wrh[idx] = 0; ucA[idx] = 0; wok[idx] = false;
        const int unit = w + 4 * idx;
        if (unit >= NUNITS) continue;
        const int layer = unit / 13, tile = unit % 13;
        const int nA = tile * 16 + m;             // A-frag gate-row
        const int uA = nA >> 2, gA = nA & 3;
        const bool ok = uA < 50;
        const int rA = gA * 50 + (ok ? uA : 0);
        const int nkt = (layer == 0) ? 2 : 4;
#pragma unroll
        for (int kt = 0; kt < 4; ++kt) {
            if (kt >= nkt) continue;
            half8 v;
#pragma unroll
            for (int j = 0; j < 8; ++j) {
                const int k = kt * 32 + g4 * 8 + j;
                float f = 0.f;
                if (ok) {
                    if (layer == 0) {
                        if (k < 50)                 f = Whh0[rA * 50 + k];
                        else if (k >= 52 && k < 55) f = Wih0[rA * 3 + (k - 52)];
                        else if (k == 55)           f = bih0[rA] + bhh0[rA];
                    } else {
                        if (k < 50)                  f = Wih1[rA * 50 + k];
                        else if (k == 55)            f = bih1[rA] + bhh1[rA];
                        else if (k >= 64 && k < 114) f = Whh1[rA * 50 + (k - 64)];
                    }
                }
                v[j] = (_Float16)f;
            }
            af[idx][kt] = v;
        }
        const int uc = tile * 4 + g4;             // this lane's output unit
        ucA[idx] = uc;
        wok[idx] = (uc < 50);                     // pads must not write (k52..55 = x/bias)
        wrh[idx] = m * ROWB + ((((layer == 0 ? 0 : 64) + uc) * 2) ^ swz);
    }

    // ---------------- loop-invariant read offsets ----------------
    int rd[4];
#pragma unroll
    for (int q = 0; q < 4; ++q) rd[q] = m * ROWB + (((q * 4 + g4) * 16) ^ swz);
    const int wrx = m * ROWB + (104 ^ swz);       // x slots k=52..55 (8B)

    // ---------------- init: zero buffers, plant x(0) and the 1.0 column ----------------
    for (int i = tid; i < 2 * HBUF / 4; i += NT) ((int*)hb)[i] = 0;
    __syncthreads();
    const bool xlane = (w == 3) && (g4 == 0);     // 16 lanes, m = batch
    const float* xbase = x + (size_t)(b0 + m) * (SEQT * 3);
    const _Float16 onef = (_Float16)1.f;
    half4v xpk;                                    // holds x(t+1) staged one step ahead
    if (xlane) {
        half4v xv;
        xv[0] = (_Float16)xbase[0]; xv[1] = (_Float16)xbase[1];
        xv[2] = (_Float16)xbase[2]; xv[3] = onef;
        *(half4v*)(hb + HBUF + wrx) = xv;         // buf1: x(0)+1.0 (phase 0 reads buf1)
        half4v z; z[0] = (_Float16)0.f; z[1] = z[0]; z[2] = z[0]; z[3] = onef;
        *(half4v*)(hb + wrx) = z;                 // buf0: 1.0 column
        xpk[0] = (_Float16)xbase[3]; xpk[1] = (_Float16)xbase[4];
        xpk[2] = (_Float16)xbase[5]; xpk[3] = onef;   // x(1)
    }
    __syncthreads();

    // ---------------- main loop: one barrier per phase ----------------
    for (int t = 0; t < SEQT; ++t) {
        const int rb = ((t + 1) & 1) * HBUF;
        const int wb = (t & 1) * HBUF;
        half8 bf[4];
#pragma unroll
        for (int q = 0; q < 4; ++q) bf[q] = *(const half8*)(hb + rb + rd[q]);

        if      (w == 0) phase_body<0>(t, bf, af, cst, hb, wb, wrh, wok, h1v);
        else if (w == 1) phase_body<1>(t, bf, af, cst, hb, wb, wrh, wok, h1v);
        else if (w == 2) phase_body<2>(t, bf, af, cst, hb, wb, wrh, wok, h1v);
        else             phase_body<3>(t, bf, af, cst, hb, wb, wrh, wok, h1v);

        if (xlane) {                              // stage x(t+1); prefetch x(t+2)
            if (t < SEQT - 1) *(half4v*)(hb + wb + wrx) = xpk;
            if (t < SEQT - 2) {
                const float* xp = xbase + (t + 2) * 3;
                xpk[0] = (_Float16)xp[0]; xpk[1] = (_Float16)xp[1];
                xpk[2] = (_Float16)xp[2]; xpk[3] = onef;
            }
        }
        __syncthreads();
    }

    // ---------------- epilogue: L1(511), reads buf1; write h1 to FC grid ----------------
    {
        half8 bf[4];
#pragma unroll
        for (int q = 0; q < 4; ++q) bf[q] = *(const half8*)(hb + HBUF + rd[q]);
        const f32x4 z4 = {0.f, 0.f, 0.f, 0.f};
#pragma unroll
        for (int idx = 0; idx < 7; ++idx) {
            const int unit = w + 4 * idx;
            if (unit < 13 || unit >= NUNITS) continue;   // L1 units only
            f32x4 p = MFMA16(af[idx][0], bf[0], z4);
            p       = MFMA16(af[idx][1], bf[1], p);
            f32x4 q = MFMA16(af[idx][2], bf[2], z4);
            q       = MFMA16(af[idx][3], bf[3], q);
            const f32x4 gv = p + q;
            const float Ei = __expf(-gv[0]), Ef = __expf(-gv[1]);
            const float Eg = __expf(2.f * gv[2]), Eo = __expf(-gv[3]);
            const float pi = 1.f + Ei, pf = 1.f + Ef, pg = 1.f + Eg, po = 1.f + Eo;
            const float r1 = fast_rcp(pi * pf);
            const float iv = pf * r1, fv = pi * r1;
            const float r2 = fast_rcp(pg * po);
            const float ov = pg * r2;
            const float tg = 1.f - 2.f * (po * r2);
            const float c  = fv * cst[idx] + iv * tg;
            const float Ec = __expf(2.f * c);
            const float hv = ov * (1.f - 2.f * fast_rcp(1.f + Ec));
            if (wok[idx]) h1g[ucA[idx]][m] = hv;
        }
    }
    __syncthreads();

    // ---------------- FC head: out[b] = sum_u h1[u]*Wfc[u] + bfc ----------------
    if (tid < BM) {
        float s = bfc[0];
        for (int u = 0; u < 50; ++u) s += h1g[u][tid] * Wfc[u];
        out[b0 + tid] = s;
    }
}

extern "C" void kernel_launch(void* const* d_in, const int* in_sizes, int n_in,
                              void* d_out, int out_size, void* d_ws, size_t ws_size,
                              hipStream_t stream)
{
    const float* x    = (const float*)d_in[0];
    const float* Wih0 = (const float*)d_in[1];
    const float* Whh0 = (const float*)d_in[2];
    const float* bih0 = (const float*)d_in[3];
    const float* bhh0 = (const float*)d_in[4];
    const float* Wih1 = (const float*)d_in[5];
    const float* Whh1 = (const float*)d_in[6];
    const float* bih1 = (const float*)d_in[7];
    const float* bhh1 = (const float*)d_in[8];
    const float* Wfc  = (const float*)d_in[9];
    const float* bfc  = (const float*)d_in[10];
    float* out = (float*)d_out;

    const int B = in_sizes[0] / (SEQT * 3);   // 4096
    lstm2_mfma7<<<B / BM, NT, 0, stream>>>(x, Wih0, Whh0, bih0, bhh0,
                                           Wih1, Whh1, bih1, bhh1, Wfc, bfc, out);
}